// Round 3
// baseline (237.017 us; speedup 1.0000x reference)
//
#include <hip/hip_runtime.h>
#include <hip/hip_bf16.h>
#include <math.h>

#define Bsz  8
#define Nseq 1024
#define Cdim 1024
#define Hh   16
#define Dd   64

typedef short short8 __attribute__((ext_vector_type(8)));
typedef float floatx4 __attribute__((ext_vector_type(4)));

__device__ __forceinline__ unsigned short f2bf(float f) {
    __hip_bfloat16 h = __float2bfloat16(f);
    return __builtin_bit_cast(unsigned short, h);
}

// async 16B global -> LDS. LDS dest is wave-uniform base + lane*16 (HW rule).
__device__ __forceinline__ void async16(const void* g, void* l) {
    __builtin_amdgcn_global_load_lds(
        (const __attribute__((address_space(1))) unsigned int*)g,
        (__attribute__((address_space(3))) unsigned int*)l, 16, 0, 0);
}

// pack two fp32 -> two bf16 (round-half-up) in one dword
__device__ __forceinline__ unsigned pack_bf16(float lo, float hi) {
    unsigned ulo = __float_as_uint(lo) + 0x8000u;
    unsigned uhi = __float_as_uint(hi) + 0x8000u;
    return __builtin_amdgcn_perm(uhi, ulo, 0x07060302);  // [ulo>>16, uhi>>16]
}

// ---------------------------------------------------------------------------
// PREP (fused): [0,8192) convert X fp32->bf16; [8192,8960) transpose w_qkv;
// [8960,9216) transpose w_proj; [9216,9344) RoPE table.
// ---------------------------------------------------------------------------
__global__ __launch_bounds__(256) void prep(
    const float* __restrict__ x, const float* __restrict__ w_qkv,
    const float* __restrict__ w_proj,
    unsigned short* __restrict__ xb, unsigned short* __restrict__ wqkvt,
    unsigned short* __restrict__ wprojt, float2* __restrict__ rope)
{
    __shared__ float T[64][65];
    const int blk = blockIdx.x;
    const int tid = threadIdx.x;

    if (blk < 8192) {
        int i = blk * 256 + tid;
        float4 v = ((const float4*)x)[i];
        ushort4 u;
        u.x = f2bf(v.x); u.y = f2bf(v.y); u.z = f2bf(v.z); u.w = f2bf(v.w);
        ((ushort4*)xb)[i] = u;
        return;
    }
    if (blk < 9216) {
        const float* in;
        unsigned short* out;
        int R = 1024, Ccols, c0, r0;
        if (blk < 8960) {
            int b2 = blk - 8192;
            in = w_qkv; out = wqkvt; Ccols = 3072;
            c0 = (b2 % 48) * 64; r0 = (b2 / 48) * 64;
        } else {
            int b2 = blk - 8960;
            in = w_proj; out = wprojt; Ccols = 1024;
            c0 = (b2 % 16) * 64; r0 = (b2 / 16) * 64;
        }
        for (int i = tid; i < 4096; i += 256) {
            int r = i >> 6, c = i & 63;
            T[r][c] = in[(size_t)(r0 + r) * Ccols + c0 + c];
        }
        __syncthreads();
        for (int i = tid; i < 4096; i += 256) {
            int rr = i >> 6, cc = i & 63;
            out[(size_t)(c0 + rr) * R + r0 + cc] = f2bf(T[cc][rr]);
        }
        return;
    }
    {
        int i = (blk - 9216) * 256 + tid;     // 0..32767
        int n = i >> 5, p = i & 31;
        float omega = __expf(-(float)p * 0.2878231366242557f);
        float sv, cv;
        sincosf((float)n * omega, &sv, &cv);
        rope[i] = make_float2(cv, sv);
    }
}

// ---------------------------------------------------------------------------
// QKV GEMM — 256x256 tile, BK=64, 8 waves (2M x 4N, wave-tile 128x64),
// 128 KiB double-buffered LDS, 4 phases per K-tile (mh,ks quadrants),
// counted vmcnt(4) once per K-tile (never 0 in steady state), setprio
// around each 16-MFMA cluster, XOR-swizzled LDS (8 x 16B slots per
// 128B row-pair line; staged via pre-swizzled global source).
//
// Half-tiles split by K (k0 = k[0:32), k1 = k[32:64)):
//   consumption: P1(mh0,ks0)/P2(mh1,ks0) read Ak0,Bk0; P3/P4 read Ak1,Bk1.
//   stage order @tile t: P1->Ak1(t+1) P2->Bk1(t+1) P3->Ak0(t+2) P4->Bk0(t+2)
//   (each target region provably dead at issue time).
//   wait @P4: vmcnt(4) retires exactly tile t+1's four halves, keeps the
//   two t+2 k0-halves in flight.
// Epilogue: RoPE-scatter q,k -> (B,H,N,D); LDS-transpose v -> vt (B,H,D,N).
// ---------------------------------------------------------------------------
#define AH(b,k) (((b)*2+(k))*8192)
#define BH(b,k) (32768+((b)*2+(k))*8192)

// stage one 16 KB k-half (256 rows x 32 k): 2 insts/wave, LDS dest linear,
// global source pre-swizzled so slot s of row-pair p holds chunk (s^(p&7)).
__device__ __forceinline__ void stage_half(const unsigned short* g, int kbase,
                                           short* dst, int wave, int lane) {
    #pragma unroll
    for (int inst = 0; inst < 2; ++inst) {
        int sb = (inst * 8 + wave) * 64;          // uniform slot base
        int slot = sb + lane;
        int p = slot >> 3, sp = (slot & 7) ^ (p & 7);
        int grow = p * 2 + (sp >> 2);
        int gcol = kbase + (sp & 3) * 8;
        async16(g + (size_t)grow * 1024 + gcol, dst + sb * 8);
    }
}

// 4 fragments (rows rbase + {0,16,32,48} + ml, k-chunk = quad) from a k-half
__device__ __forceinline__ void ld4(short8 d[4], const short* hb, int rbase,
                                    int ml, int quad) {
    #pragma unroll
    for (int f = 0; f < 4; ++f) {
        int row = rbase + f * 16 + ml;
        int p = row >> 1;
        int sl = (((row & 1) << 2) | quad) ^ (p & 7);
        d[f] = *(const short8*)&hb[p * 64 + sl * 8];
    }
}

__device__ __forceinline__ void mma16(floatx4 acc[8][4], int mb,
                                      const short8 ar[4], const short8 br[4]) {
    #pragma unroll
    for (int f = 0; f < 4; ++f)
        #pragma unroll
        for (int n = 0; n < 4; ++n)
            acc[mb + f][n] = __builtin_amdgcn_mfma_f32_16x16x32_bf16(
                ar[f], br[n], acc[mb + f][n], 0, 0, 0);
}

#define VMW4 asm volatile("s_waitcnt vmcnt(4)" ::: "memory")
#define VMW0 asm volatile("s_waitcnt vmcnt(0)" ::: "memory")
#define BARA do { __builtin_amdgcn_s_barrier();                          \
                  asm volatile("s_waitcnt lgkmcnt(0)" ::: "memory");     \
                  __builtin_amdgcn_sched_barrier(0); } while (0)
#define BARB __builtin_amdgcn_s_barrier()

#define KT(T, S12, S34, WAITX) {                                          \
    const int bu = (T) & 1, nb = bu ^ 1;                                  \
    /* P1: (mh0, ks0) */                                                  \
    ld4(ar, SM + AH(bu,0), wm * 128,      ml, quad);                      \
    ld4(br, SM + BH(bu,0), wn * 64,       ml, quad);                      \
    if (S12) stage_half(Agp, ((T)+1)*64 + 32, SM + AH(nb,1), wave, lane); \
    BARA; __builtin_amdgcn_s_setprio(1); mma16(acc, 0, ar, br);           \
    __builtin_amdgcn_s_setprio(0); BARB;                                  \
    /* P2: (mh1, ks0) — B reused from regs */                             \
    ld4(ar, SM + AH(bu,0), wm * 128 + 64, ml, quad);                      \
    if (S12) stage_half(Bgp, ((T)+1)*64 + 32, SM + BH(nb,1), wave, lane); \
    BARA; __builtin_amdgcn_s_setprio(1); mma16(acc, 4, ar, br);           \
    __builtin_amdgcn_s_setprio(0); BARB;                                  \
    /* P3: (mh0, ks1) */                                                  \
    ld4(ar, SM + AH(bu,1), wm * 128,      ml, quad);                      \
    ld4(br, SM + BH(bu,1), wn * 64,       ml, quad);                      \
    if (S34) stage_half(Agp, ((T)+2)*64,      SM + AH(bu,0), wave, lane); \
    BARA; __builtin_amdgcn_s_setprio(1); mma16(acc, 0, ar, br);           \
    __builtin_amdgcn_s_setprio(0); BARB;                                  \
    /* P4: (mh1, ks1) */                                                  \
    ld4(ar, SM + AH(bu,1), wm * 128 + 64, ml, quad);                      \
    if (S34) stage_half(Bgp, ((T)+2)*64,      SM + BH(bu,0), wave, lane); \
    WAITX;                                                                \
    BARA; __builtin_amdgcn_s_setprio(1); mma16(acc, 4, ar, br);           \
    __builtin_amdgcn_s_setprio(0); BARB;                                  \
}

__global__ __launch_bounds__(512, 2) void gemm_qkv(
    const unsigned short* __restrict__ A, const unsigned short* __restrict__ Bt,
    const float2* __restrict__ rope,
    unsigned short* __restrict__ qb, unsigned short* __restrict__ kb,
    unsigned short* __restrict__ vtb)
{
    __shared__ __attribute__((aligned(16))) short SM[65536];   // 128 KiB
    const int tid  = threadIdx.x;
    const int wave = tid >> 6, lane = tid & 63;
    const int ml = lane & 15, quad = lane >> 4;
    const int wm = wave >> 2, wn = wave & 3;

    // XCD-aware bijective remap (384 blocks, 384 % 8 == 0)
    int lin = blockIdx.y * 12 + blockIdx.x;
    lin = (lin & 7) * 48 + (lin >> 3);
    const int bm = (lin / 12) * 256, bn = (lin % 12) * 256;

    const unsigned short* Agp = A  + (size_t)bm * 1024;
    const unsigned short* Bgp = Bt + (size_t)bn * 1024;

    floatx4 acc[8][4] = {};
    short8 ar[4], br[4];

    // prologue: tile0 (4 halves) + tile1 k0-halves; keep the latter in flight
    stage_half(Agp,  0, SM + AH(0,0), wave, lane);
    stage_half(Bgp,  0, SM + BH(0,0), wave, lane);
    stage_half(Agp, 32, SM + AH(0,1), wave, lane);
    stage_half(Bgp, 32, SM + BH(0,1), wave, lane);
    stage_half(Agp, 64, SM + AH(1,0), wave, lane);
    stage_half(Bgp, 64, SM + BH(1,0), wave, lane);
    VMW4;
    BARB;

    KT(0, 1, 1, VMW4)  KT(1, 1, 1, VMW4)  KT(2, 1, 1, VMW4)  KT(3, 1, 1, VMW4)
    KT(4, 1, 1, VMW4)  KT(5, 1, 1, VMW4)  KT(6, 1, 1, VMW4)  KT(7, 1, 1, VMW4)
    KT(8, 1, 1, VMW4)  KT(9, 1, 1, VMW4)  KT(10, 1, 1, VMW4) KT(11, 1, 1, VMW4)
    KT(12, 1, 1, VMW4) KT(13, 1, 1, VMW4) KT(14, 1, 0, VMW0) KT(15, 0, 0, (void)0)

    // ---- epilogue ----
    const int region = bn >> 10;              // 0=q, 1=k, 2=v (BN=256 divides 1024)
    const int b  = bm >> 10;
    const int n0 = bm & 1023;
    if (region < 2) {
        // stage rope slice rows n0..n0+255: Rs[rl][p], 8192 float2 = 64 KB
        float2* Rs = (float2*)SM;
        for (int i = tid; i < 8192; i += 512)
            Rs[i] = rope[(size_t)(n0 + (i >> 5)) * 32 + (i & 31)];
        __syncthreads();
        unsigned short* dst = (region == 0) ? qb : kb;
        const float scale = (region == 0) ? 0.125f : 1.f;
        const float sgn = (ml & 1) ? 1.f : -1.f;
        #pragma unroll
        for (int ni = 0; ni < 4; ++ni) {
            int jj = (bn & 1023) + wn * 64 + ni * 16 + ml;
            int h = jj >> 6, d = jj & 63, pp = d >> 1;
            #pragma unroll
            for (int mi = 0; mi < 8; ++mi)
                #pragma unroll
                for (int r = 0; r < 4; ++r) {
                    int rl = wm * 128 + mi * 16 + quad * 4 + r;
                    float val = acc[mi][ni][r];
                    float partner = __shfl_xor(val, 1);
                    float2 cs = Rs[rl * 32 + pp];
                    dst[(((size_t)(b * Hh + h)) * Nseq + n0 + rl) * Dd + d] =
                        f2bf((val * cs.x + sgn * partner * cs.y) * scale);
                }
        }
    } else {
        // V: transpose via LDS T[256][136], two 128-row passes -> vt (B,H,D,N)
        short* T = SM;
        const int hb = (bn & 1023) >> 6;      // 4 heads per 256-col tile
        #pragma unroll
        for (int hw = 0; hw < 2; ++hw) {
            if (hw) __syncthreads();          // prior pass reads done
            if (wm == hw) {
                #pragma unroll
                for (int ni = 0; ni < 4; ++ni) {
                    int c = wn * 64 + ni * 16 + ml;
                    #pragma unroll
                    for (int mi = 0; mi < 8; ++mi) {
                        uint2 pk;
                        pk.x = pack_bf16(acc[mi][ni][0], acc[mi][ni][1]);
                        pk.y = pack_bf16(acc[mi][ni][2], acc[mi][ni][3]);
                        *(uint2*)&T[c * 136 + mi * 16 + quad * 4] = pk;
                    }
                }
            }
            __syncthreads();
            #pragma unroll
            for (int i = 0; i < 16; ++i) {
                int idx = i * 512 + tid;      // 0..8191 ushort4 units
                int c = idx >> 5, seg = idx & 31;
                ushort4 v4 = *(const ushort4*)&T[c * 136 + seg * 4];
                int h = hb + (c >> 6), d = c & 63;
                *(ushort4*)(vtb + (((size_t)(b * Hh + h)) * Dd + d) * Nseq
                            + n0 + hw * 128 + seg * 4) = v4;
            }
        }
    }
}

// ---------------------------------------------------------------------------
// Output-projection GEMM (proven m97-style 128x128, BK=64, 4 waves): +bias,
// fp32 out. XCD-aware block swizzle (512 blocks % 8 == 0).
// ---------------------------------------------------------------------------
__global__ __launch_bounds__(256) void gemm_proj(
    const unsigned short* __restrict__ A, const unsigned short* __restrict__ Bt,
    const float* __restrict__ bias, float* __restrict__ out)
{
    const int K = 1024;
    __shared__ short SM[2][128][64];
    const int tid  = threadIdx.x;
    const int wave = tid >> 6, lane = tid & 63;
    const int ml = lane & 15, quad = lane >> 4;
    const int wm = wave >> 1, wn = wave & 1;

    int lin = blockIdx.y * gridDim.x + blockIdx.x;
    const int nwg = gridDim.x * gridDim.y;
    lin = (lin & 7) * (nwg >> 3) + (lin >> 3);
    const int bx = lin % gridDim.x, by = lin / gridDim.x;
    const int bm = by * 128, bn = bx * 128;

    const int lr     = lane >> 3;
    const int lchunk = ((lane & 7) ^ lr) * 8;

    floatx4 acc[4][4] = {};

    for (int k0 = 0; k0 < K; k0 += 64) {
        #pragma unroll
        for (int t = 0; t < 4; ++t) {
            int r8  = (wave * 4 + t) * 8;
            int row = r8 + lr;
            async16(A  + (size_t)(bm + row) * K + k0 + lchunk, &SM[0][r8][0]);
            async16(Bt + (size_t)(bn + row) * K + k0 + lchunk, &SM[1][r8][0]);
        }
        __syncthreads();

        #pragma unroll
        for (int ks = 0; ks < 2; ++ks) {
            const int sl = ((ks * 4 + quad) ^ (ml & 7)) * 8;
            short8 araw[4], braw[4];
            #pragma unroll
            for (int mi = 0; mi < 4; ++mi)
                araw[mi] = *(const short8*)&SM[0][wm * 64 + mi * 16 + ml][sl];
            #pragma unroll
            for (int ni = 0; ni < 4; ++ni)
                braw[ni] = *(const short8*)&SM[1][wn * 64 + ni * 16 + ml][sl];
            #pragma unroll
            for (int mi = 0; mi < 4; ++mi)
                #pragma unroll
                for (int ni = 0; ni < 4; ++ni)
                    acc[mi][ni] = __builtin_amdgcn_mfma_f32_16x16x32_bf16(
                        araw[mi], braw[ni], acc[mi][ni], 0, 0, 0);
        }
        __syncthreads();
    }

    #pragma unroll
    for (int ni = 0; ni < 4; ++ni) {
        int col = bn + wn * 64 + ni * 16 + ml;
        float bv = bias[col];
        #pragma unroll
        for (int mi = 0; mi < 4; ++mi)
            #pragma unroll
            for (int r = 0; r < 4; ++r) {
                int row = bm + wm * 64 + mi * 16 + quad * 4 + r;
                out[(size_t)row * 1024 + col] = acc[mi][ni][r] + bv;
            }
    }
}

// ---------------------------------------------------------------------------
// MFMA flash attention: no-max softmax, 128 q-rows/block, software-pipelined
// V(kt)/K(kt+1) staging, Q fragments hoisted to registers, LDS union
// (34 KB -> 4 blocks/CU), setprio around MFMA clusters.
// ---------------------------------------------------------------------------
__global__ __launch_bounds__(256, 4) void attn_flash_mfma(
    const unsigned short* __restrict__ qb, const unsigned short* __restrict__ kb,
    const unsigned short* __restrict__ vt, unsigned short* __restrict__ ao)
{
    const int bh  = blockIdx.x;   // 0..127
    const int qt  = blockIdx.y;   // 0..7
    const int tid = threadIdx.x;
    const int wave = tid >> 6, lane = tid & 63;
    const int ml = lane & 15, quad = lane >> 4;
    const int lr = lane >> 3;
    const int lc = ((lane & 7) ^ lr) * 8;

    __shared__ __attribute__((aligned(16))) short SMEM[17408];
    short (*Ks)[64] = (short(*)[64])SMEM;                 // 4096 shorts
    short* U = SMEM + 4096;
    short (*Qs)[64] = (short(*)[64])U;                    // prologue only
    short (*Vs)[64] = (short(*)[64])U;                    // 4096 shorts
    short (*Ps)[32][72] = (short(*)[32][72])(U + 4096);   // 9216 shorts

    const size_t hbase = (size_t)bh * (Nseq * Dd);
    const size_t vbase = (size_t)bh * 64;
    const int q0 = qt * 128;
    const int wq = wave * 32;
    const int wk = wave * 16;

    #pragma unroll
    for (int t = 0; t < 4; ++t)
        async16(qb + hbase + (size_t)(q0 + wq + t * 8 + lr) * 64 + lc, &Qs[wq + t * 8][0]);
    async16(kb + hbase + (size_t)(wk + lr) * 64 + lc,     &Ks[wk][0]);
    async16(kb + hbase + (size_t)(wk + 8 + lr) * 64 + lc, &Ks[wk + 8][0]);
    __syncthreads();

    short8 qfr[2][2];
    #pragma unroll
    for (int ks = 0; ks < 2; ++ks) {
        const int sl = ((ks * 4 + quad) ^ (ml & 7)) * 8;
        qfr[ks][0] = *(const short8*)&Qs[wq + ml][sl];
        qfr[ks][1] = *(const short8*)&Qs[wq + 16 + ml][sl];
    }
    __syncthreads();   // qfr reads complete in all waves: U reusable (Vs/Ps)

    float l0 = 0.f, l1 = 0.f;
    floatx4 o[2][4] = {};

    for (int kt = 0; kt < 16; ++kt) {
        const int k0r = kt * 64;
        async16(vt + (vbase + wk + lr) * Nseq + k0r + lc,     &Vs[wk][0]);
        async16(vt + (vbase + wk + 8 + lr) * Nseq + k0r + lc, &Vs[wk + 8][0]);

        floatx4 st[2][4] = {};
        __builtin_amdgcn_s_setprio(1);
        #pragma unroll
        for (int ks = 0; ks < 2; ++ks) {
            const int sl = ((ks * 4 + quad) ^ (ml & 7)) * 8;
            #pragma unroll
            for (int kbk = 0; kbk < 4; ++kbk) {
                short8 kf = *(const short8*)&Ks[kbk * 16 + ml][sl];
                st[0][kbk] = __builtin_amdgcn_mfma_f32_16x16x32_bf16(kf, qfr[ks][0], st[0][kbk], 0, 0, 0);
                st[1][kbk] = __builtin_amdgcn_mfma_f32_16x16x32_bf16(kf, qfr[ks][1], st[1][kbk], 0, 0, 0);
            }
        }
        __builtin_amdgcn_s_setprio(0);

        #pragma unroll
        for (int qg = 0; qg < 2; ++qg) {
            float lacc = 0.f;
            #pragma unroll
            for (int kbk = 0; kbk < 4; ++kbk) {
                float e0 = __expf(st[qg][kbk][0]);
                float e1 = __expf(st[qg][kbk][1]);
                float e2 = __expf(st[qg][kbk][2]);
                float e3 = __expf(st[qg][kbk][3]);
                lacc += (e0 + e1) + (e2 + e3);
                uint2 pk;
                pk.x = pack_bf16(e0, e1);
                pk.y = pack_bf16(e2, e3);
                *(uint2*)&Ps[wave][qg * 16 + ml][kbk * 16 + quad * 4] = pk;
            }
            if (qg == 0) l0 += lacc; else l1 += lacc;
        }
        __syncthreads();   // V(kt) visible; all waves done with Ks(kt)

        if (kt < 15) {
            const int k1r = k0r + 64;
            async16(kb + hbase + (size_t)(k1r + wk + lr) * 64 + lc,     &Ks[wk][0]);
            async16(kb + hbase + (size_t)(k1r + wk + 8 + lr) * 64 + lc, &Ks[wk + 8][0]);
        }

        __builtin_amdgcn_s_setprio(1);
        #pragma unroll
        for (int ks = 0; ks < 2; ++ks) {
            const int sl = ((ks * 4 + quad) ^ (ml & 7)) * 8;
            short8 pf0 = *(const short8*)&Ps[wave][ml][ks * 32 + quad * 8];
            short8 pf1 = *(const short8*)&Ps[wave][16 + ml][ks * 32 + quad * 8];
            #pragma unroll
            for (int nt = 0; nt < 4; ++nt) {
                short8 vf = *(const short8*)&Vs[nt * 16 + ml][sl];
                o[0][nt] = __builtin_amdgcn_mfma_f32_16x16x32_bf16(pf0, vf, o[0][nt], 0, 0, 0);
                o[1][nt] = __builtin_amdgcn_mfma_f32_16x16x32_bf16(pf1, vf, o[1][nt], 0, 0, 0);
            }
        }
        __builtin_amdgcn_s_setprio(0);
        if (kt < 15)
            __syncthreads();
    }

    l0 += __shfl_xor(l0, 16);
    l0 += __shfl_xor(l0, 32);
    l1 += __shfl_xor(l1, 16);
    l1 += __shfl_xor(l1, 32);

    const int b = bh >> 4, h = bh & 15;
    #pragma unroll
    for (int qg = 0; qg < 2; ++qg) {
        float lsrc = (qg == 0) ? l0 : l1;
        #pragma unroll
        for (int r = 0; r < 4; ++r) {
            float lq = __shfl(lsrc, quad * 4 + r);
            float inv = 1.f / lq;
            int q = q0 + wq + qg * 16 + quad * 4 + r;
            size_t rowbase = ((size_t)(b * Nseq + q)) * Cdim + h * Dd;
            #pragma unroll
            for (int nt = 0; nt < 4; ++nt)
                ao[rowbase + nt * 16 + ml] = f2bf(o[qg][nt][r] * inv);
        }
    }
}

extern "C" void kernel_launch(void* const* d_in, const int* in_sizes, int n_in,
                              void* d_out, int out_size, void* d_ws, size_t ws_size,
                              hipStream_t stream) {
    const float* x      = (const float*)d_in[0];
    const float* w_qkv  = (const float*)d_in[1];
    const float* w_proj = (const float*)d_in[2];
    const float* b_proj = (const float*)d_in[3];
    float* out = (float*)d_out;

    const size_t M8 = (size_t)8 * 1024 * 1024;
    unsigned short* qb     = (unsigned short*)d_ws;
    unsigned short* kb     = qb + M8;
    unsigned short* vt     = kb + M8;                  // (B,H,D,N)
    unsigned short* xb     = vt + M8;                  // reused as aob
    unsigned short* wqkvt  = xb + M8;                  // 3072 x 1024
    unsigned short* wprojt = wqkvt + 3 * 1024 * 1024;  // 1024 x 1024
    float2*         rope   = (float2*)(wprojt + 1024 * 1024);  // 1024 x 32
    unsigned short* aob    = xb;   // alias: xb dead after gemm_qkv

    prep<<<9344, 256, 0, stream>>>(x, w_qkv, w_proj, xb, wqkvt, wprojt, rope);

    gemm_qkv<<<dim3(12, 32), 512, 0, stream>>>(xb, wqkvt, rope, qb, kb, vt);

    attn_flash_mfma<<<dim3(128, 8), 256, 0, stream>>>(qb, kb, vt, aob);

    gemm_proj<<<dim3(8, 64), 256, 0, stream>>>(aob, wprojt, b_proj, out);
}